// Round 11
// baseline (45.150 us; speedup 1.0000x reference)
//
#include <hip/hip_runtime.h>
#include <hip/hip_fp16.h>

#define NQ 18
#define QDIM (1 << NQ)      // 262144
#define NB 8
#define NL 4

typedef unsigned u32;
typedef unsigned long long u64;

#define DPP_XOR1 0xB1   // quad_perm [1,0,3,2]  (lane bit 0)
#define DPP_XOR2 0x4E   // quad_perm [2,3,0,1]  (lane bit 1)

// tan-form butterfly: a' = a - i t b ; b' = b - i t a (cos^k deferred into ptab)
__device__ __forceinline__ void tbfly(float2& a, float2& b, float t) {
  float nax = fmaf(t, b.y, a.x);
  float nay = fmaf(-t, b.x, a.y);
  float nbx = fmaf(t, a.y, b.x);
  float nby = fmaf(-t, a.x, b.y);
  a = make_float2(nax, nay); b = make_float2(nbx, nby);
}
__device__ __forceinline__ void tstage8(float2* v, int m, float t) {
#pragma unroll
  for (int i = 0; i < 8; ++i)
    if (!(i & m)) tbfly(v[i], v[i | m], t);
}
template <int CTRL>
__device__ __forceinline__ void dppstage8(float2* v, float t) {
#pragma unroll
  for (int k = 0; k < 8; ++k) {
    float ox = __int_as_float(
        __builtin_amdgcn_mov_dpp(__float_as_int(v[k].x), CTRL, 0xF, 0xF, true));
    float oy = __int_as_float(
        __builtin_amdgcn_mov_dpp(__float_as_int(v[k].y), CTRL, 0xF, 0xF, true));
    v[k] = make_float2(fmaf(t, oy, v[k].x), fmaf(-t, ox, v[k].y));
  }
}
__device__ __forceinline__ void shfl32stage8(float2* v, float t) {
#pragma unroll
  for (int k = 0; k < 8; ++k) {
    float ox = __shfl_xor(v[k].x, 32, 64);
    float oy = __shfl_xor(v[k].y, 32, 64);
    v[k] = make_float2(fmaf(t, oy, v[k].x), fmaf(-t, ox, v[k].y));
  }
}
// 6-bit mix: 3 reg bits + lane bits 0,1 (dpp) + lane bit 5 (shfl). Stages commute.
__device__ __forceinline__ void mix6(float2* v, float t) {
  tstage8(v, 1, t); tstage8(v, 2, t); tstage8(v, 4, t);
  dppstage8<DPP_XOR1>(v, t); dppstage8<DPP_XOR2>(v, t);
  shfl32stage8(v, t);
}
__device__ __forceinline__ void pmul(float2& a, float2 p) {
  a = make_float2(a.x * p.x - a.y * p.y, a.x * p.y + a.y * p.x);
}
// LDS swizzle: XOR byte bits 4-6 with bits 7-9. Involution, both sides.
__device__ __forceinline__ int swz(int byte) { return byte ^ (((byte >> 7) & 7) << 4); }

__device__ __forceinline__ float2 h2f(u32 u) {
  __half2 h; *(u32*)&h = u; return __half22float2(h);
}
__device__ __forceinline__ u32 f2h(float2 f) {
  __half2 h = __float22half2_rn(f); return *(u32*)&h;
}

// sc0 (L1-bypass) state loads: relaxed agent-scope atomics emit no cache flush
// but read the (shared, same-XCD) L2 directly.
__device__ __forceinline__ void ld_state8(const u32* p, float2* v) {
  u64* q = (u64*)p;
#pragma unroll
  for (int i = 0; i < 4; ++i) {
    const u64 wv = __hip_atomic_load(q + i, __ATOMIC_RELAXED, __HIP_MEMORY_SCOPE_AGENT);
    v[2*i]   = h2f((u32)wv);
    v[2*i+1] = h2f((u32)(wv >> 32));
  }
}
__device__ __forceinline__ float2 ld_state1(const u32* p) {
  return h2f(__hip_atomic_load((u32*)p, __ATOMIC_RELAXED, __HIP_MEMORY_SCOPE_AGENT));
}

// fence-free same-XCD batch barrier (32 blocks). Stores are visible to peers via
// the shared per-XCD L2 once vmcnt drains; NO acquire/release (no L2 wbinv).
__device__ __forceinline__ void batchbar(u32* cnt) {
  asm volatile("s_waitcnt vmcnt(0) lgkmcnt(0)" ::: "memory");  // every wave drains
  __syncthreads();
  if (threadIdx.x == 0) {
    __hip_atomic_fetch_add(cnt, 1u, __ATOMIC_RELAXED, __HIP_MEMORY_SCOPE_AGENT);
    int guard = 0;
    while (__hip_atomic_load(cnt, __ATOMIC_RELAXED, __HIP_MEMORY_SCOPE_AGENT) < 32u) {
      __builtin_amdgcn_s_sleep(2);
      if (++guard > (1 << 21)) break;  // fail loudly, never hang
    }
  }
  __syncthreads();
}

// ---------------- low body: element bits 0..11 of one 4096-elem tile ----------
//  A: le = tid<<3 | j   (reg j = bits 0-2; dpp = 3,4; shfl32 = 8)  <- global I/O
//  B: le = j<<9 | constB (reg j = bits 9-11; dpp = 5,6; shfl32 = 7)
template <int MODE>
__device__ __forceinline__
void low_body(const int tid, const int b, const int blk6,
              const float tf0, const float tf1, const float escale,
              float2* __restrict__ swapb, const float2* __restrict__ ptab,
              const unsigned* __restrict__ smask, const unsigned* __restrict__ sfull,
              const int* __restrict__ sdeg, float* __restrict__ wsum,
              unsigned char* __restrict__ hp8, u32* __restrict__ state,
              float* __restrict__ out) {
  const int l = tid & 63, w = tid >> 6;
  const size_t bb = (size_t)b << NQ;
  const int lbase = blk6 << 12;
  char* L = (char*)swapb;
  const int constB = ((w >> 2) << 8) | (((l >> 5) & 1) << 7) | (((l >> 1) & 1) << 6)
                   | ((l & 1) << 5) | ((w & 3) << 3) | ((l >> 2) & 7);
  const int bBbase = constB << 3;

  float2 v[8];

  if (MODE == 0) {
    // hp via gray code over element bits 0-2 (A regs)
    unsigned d = (unsigned)(lbase | (tid << 3));
    int hp = 0;
#pragma unroll
    for (int uq = 0; uq < NQ; ++uq) {
      const unsigned f = (d >> (17 - uq)) & 1u;
      hp += __popc(smask[uq] & (d ^ (0u - f)));
    }
    u64 pk = (u64)hp;
    int j = 0;
#pragma unroll
    for (int i = 1; i < 8; ++i) {
      const int p = __ffs(i) - 1;
      const int old = (int)((d >> p) & 1u);
      const int nb1 = __popc(sfull[p] & d);
      hp += old ? (2 * nb1 - sdeg[p]) : (sdeg[p] - 2 * nb1);
      d ^= 1u << p; j ^= 1 << p;
      pk |= (u64)hp << (8 * j);
    }
    *(u64*)(hp8 + bb + (size_t)(lbase + (tid << 3))) = pk;
#pragma unroll
    for (int jj = 0; jj < 8; ++jj)
      v[jj] = ptab[(int)((pk >> (8 * jj)) & 255)];
    mix6(v, tf0);                                 // A bits {0-4,8}
#pragma unroll
    for (int q = 0; q < 4; ++q)                   // swap A -> B
      *(float4*)(L + swz((tid << 6) | (q << 4))) =
          make_float4(v[2*q].x, v[2*q].y, v[2*q+1].x, v[2*q+1].y);
    __syncthreads();
#pragma unroll
    for (int jj = 0; jj < 8; ++jj)
      v[jj] = *(const float2*)(L + swz((jj << 12) + bBbase));
    mix6(v, tf0);                                 // B bits {5,6,7,9,10,11}
#pragma unroll
    for (int jj = 0; jj < 8; ++jj)                // swap B -> A
      *(float2*)(L + swz((jj << 12) + bBbase)) = v[jj];
    __syncthreads();
#pragma unroll
    for (int q = 0; q < 4; ++q) {
      const float4 f = *(const float4*)(L + swz((tid << 6) | (q << 4)));
      v[2*q]   = make_float2(f.x, f.y);
      v[2*q+1] = make_float2(f.z, f.w);
    }
    uint4* gdst = (uint4*)(state + bb + lbase + (tid << 3));
    gdst[0] = make_uint4(f2h(v[0]), f2h(v[1]), f2h(v[2]), f2h(v[3]));
    gdst[1] = make_uint4(f2h(v[4]), f2h(v[5]), f2h(v[6]), f2h(v[7]));
    return;
  }

  // MODE 1 / 2: load @A (sc0), mix6A(t0), swap -> B, mix6B(t0)
  ld_state8(state + bb + lbase + (tid << 3), v);
  mix6(v, tf0);                                   // A bits {0-4,8}
#pragma unroll
  for (int q = 0; q < 4; ++q)
    *(float4*)(L + swz((tid << 6) | (q << 4))) =
        make_float4(v[2*q].x, v[2*q].y, v[2*q+1].x, v[2*q+1].y);
  __syncthreads();
#pragma unroll
  for (int jj = 0; jj < 8; ++jj)
    v[jj] = *(const float2*)(L + swz((jj << 12) + bBbase));
  mix6(v, tf0);                                   // B bits {5,6,7,9,10,11}

  if (MODE == 1) {
    const unsigned char* hq = hp8 + bb + (size_t)(lbase + constB);
#pragma unroll
    for (int jj = 0; jj < 8; ++jj)
      pmul(v[jj], ptab[hq[jj << 9]]);             // diagonal @B (hp write-once: plain)
    mix6(v, tf1);                                 // B bits
#pragma unroll
    for (int jj = 0; jj < 8; ++jj)                // swap B -> A
      *(float2*)(L + swz((jj << 12) + bBbase)) = v[jj];
    __syncthreads();
#pragma unroll
    for (int q = 0; q < 4; ++q) {
      const float4 f = *(const float4*)(L + swz((tid << 6) | (q << 4)));
      v[2*q]   = make_float2(f.x, f.y);
      v[2*q+1] = make_float2(f.z, f.w);
    }
    mix6(v, tf1);                                 // A bits
    uint4* gdst = (uint4*)(state + bb + lbase + (tid << 3));
    gdst[0] = make_uint4(f2h(v[0]), f2h(v[1]), f2h(v[2]), f2h(v[3]));
    gdst[1] = make_uint4(f2h(v[4]), f2h(v[5]), f2h(v[6]), f2h(v[7]));
  } else {  // MODE 2: energy @B; scale before squaring
    const unsigned char* hq = hp8 + bb + (size_t)(lbase + constB);
    float acc = 0.f;
#pragma unroll
    for (int jj = 0; jj < 8; ++jj) {
      const float h = (float)hq[jj << 9];
      const float wx = v[jj].x * escale, wy = v[jj].y * escale;
      acc = fmaf(wx * wx + wy * wy, h, acc);
    }
#pragma unroll
    for (int m = 1; m <= 32; m <<= 1) acc += __shfl_xor(acc, m, 64);
    if (l == 0) wsum[w] = acc;
    __syncthreads();
    if (tid == 0) {
      float s = 0.f;
#pragma unroll
      for (int i = 0; i < 8; ++i) s += wsum[i];
      atomicAdd(out + b, s);
    }
    __syncthreads();   // protect wsum before next tile
  }
}

// ---------------- high body: element bits 12..17 of one 64x64 tile ------------
__device__ __forceinline__
void high_body(const int tid, const int b, const int mid,
               const float tf0, const float tf1,
               float2* __restrict__ swapb, const float2* __restrict__ ptab,
               const unsigned char* __restrict__ hp8, u32* __restrict__ state) {
  const int col = tid & 63, w = tid >> 6;
  const size_t bb = (size_t)b << NQ;
  const int cbase = (mid << 6) | col;
  float2 v[8];

#pragma unroll
  for (int j = 0; j < 8; ++j)
    v[j] = ld_state1(state + bb + ((size_t)((w << 3) | j) << 12) + cbase);
  tstage8(v, 1, tf0); tstage8(v, 2, tf0); tstage8(v, 4, tf0);   // bits 12-14
#pragma unroll
  for (int j = 0; j < 8; ++j)
    swapb[(((w << 3) | j) << 6) | col] = v[j];
  __syncthreads();
#pragma unroll
  for (int j = 0; j < 8; ++j)
    v[j] = swapb[(((j << 3) | w) << 6) | col];
  tstage8(v, 1, tf0); tstage8(v, 2, tf0); tstage8(v, 4, tf0);   // bits 15-17
#pragma unroll
  for (int j = 0; j < 8; ++j) {
    const int h = hp8[bb + ((size_t)((j << 3) | w) << 12) + cbase];
    pmul(v[j], ptab[h]);
  }
  tstage8(v, 1, tf1); tstage8(v, 2, tf1); tstage8(v, 4, tf1);   // bits 15-17
#pragma unroll
  for (int j = 0; j < 8; ++j)
    swapb[(((j << 3) | w) << 6) | col] = v[j];
  __syncthreads();
#pragma unroll
  for (int j = 0; j < 8; ++j)
    v[j] = swapb[(((w << 3) | j) << 6) | col];
  tstage8(v, 1, tf1); tstage8(v, 2, tf1); tstage8(v, 4, tf1);   // bits 12-14
#pragma unroll
  for (int j = 0; j < 8; ++j)
    state[bb + ((size_t)((w << 3) | j) << 12) + cbase] = f2h(v[j]);
}

__global__ void k_init(u32* __restrict__ bar, float* __restrict__ out) {
  const int t = threadIdx.x;
  if (t < 128) bar[t] = 0u;
  if (t >= 128 && t < 128 + NB) out[t - 128] = 0.f;
}

// 256 blocks x 512 thr: 1 block/CU guaranteed resident (32KB LDS). Per batch:
// 32 blocks on ONE XCD (b = blockIdx&7), 2 tiles/block/phase.
__global__ __launch_bounds__(512)
void k_fused(const float* __restrict__ betas, const float* __restrict__ adj,
             unsigned char* __restrict__ hp8, u32* __restrict__ state,
             float* __restrict__ out, u32* __restrict__ bar) {
  __shared__ float2 swapb[4096];   // 32 KB
  __shared__ float2 ptab[160];
  __shared__ unsigned smask[NQ];
  __shared__ unsigned sfull[3];
  __shared__ int sdeg[3];
  __shared__ float wsum[8];

  const int tid = threadIdx.x;
  const int b = blockIdx.x & 7;        // XCD-aligned batch
  const int idx = blockIdx.x >> 3;     // 0..31 within batch
  u32* mybar = bar + b * 16;

  // per-layer trig, once
  float tf[4], cp6[4], cp12[4];
#pragma unroll
  for (int t = 0; t < 4; ++t) {
    float s, c; sincosf(betas[b * NL + t], &s, &c);
    tf[t] = s / c;
    const float c2 = c * c;
    cp6[t] = c2 * c2 * c2;
    cp12[t] = cp6[t] * cp6[t];
  }

  // ---- P0: D1 + L0 ----
  if (tid < NQ) {
    unsigned m = 0;
    const float* row = adj + ((size_t)b * NQ + tid) * NQ;
    for (int vq = tid + 1; vq < NQ; ++vq)
      if (row[vq] > 0.5f) m |= 1u << (NQ - 1 - vq);
    smask[tid] = m;
  }
  {
    const float sc = 0.001953125f * cp12[0];
    if (tid < 160) {
      float ss, cc; sincosf((float)tid, &ss, &cc);
      ptab[tid] = make_float2(cc * sc, -ss * sc);
    }
  }
  __syncthreads();
  if (tid < 3) {
    unsigned fm = smask[17 - tid];
    for (int uq = 0; uq < NQ; ++uq)
      if ((smask[uq] >> tid) & 1u) fm |= 1u << (17 - uq);
    sfull[tid] = fm; sdeg[tid] = __popc(fm);
  }
  __syncthreads();
#pragma unroll
  for (int s = 0; s < 2; ++s) {
    if (s) __syncthreads();
    low_body<0>(tid, b, (idx << 1) | s, tf[0], 0.f, 0.f, swapb, ptab, smask,
                sfull, sdeg, wsum, hp8, state, out);
  }
  batchbar(mybar + 0);

  // ---- P1: H0 D2 H1 ----
  {
    const float sc = cp6[0] * cp6[1];
    if (tid < 160) {
      float ss, cc; sincosf((float)tid, &ss, &cc);
      ptab[tid] = make_float2(cc * sc, -ss * sc);
    }
  }
  __syncthreads();
#pragma unroll
  for (int s = 0; s < 2; ++s) {
    if (s) __syncthreads();
    high_body(tid, b, (idx << 1) | s, tf[0], tf[1], swapb, ptab, hp8, state);
  }
  batchbar(mybar + 1);

  // ---- P2: L1 D3 L2 ----
  {
    const float sc = cp12[1] * cp12[2];
    if (tid < 160) {
      float ss, cc; sincosf((float)tid, &ss, &cc);
      ptab[tid] = make_float2(cc * sc, -ss * sc);
    }
  }
  __syncthreads();
#pragma unroll
  for (int s = 0; s < 2; ++s) {
    if (s) __syncthreads();
    low_body<1>(tid, b, (idx << 1) | s, tf[1], tf[2], 0.f, swapb, ptab, smask,
                sfull, sdeg, wsum, hp8, state, out);
  }
  batchbar(mybar + 2);

  // ---- P3: H2 D4 H3 ----
  {
    const float sc = cp6[2] * cp6[3];
    if (tid < 160) {
      float ss, cc; sincosf((float)tid, &ss, &cc);
      ptab[tid] = make_float2(cc * sc, -ss * sc);
    }
  }
  __syncthreads();
#pragma unroll
  for (int s = 0; s < 2; ++s) {
    if (s) __syncthreads();
    high_body(tid, b, (idx << 1) | s, tf[2], tf[3], swapb, ptab, hp8, state);
  }
  batchbar(mybar + 3);

  // ---- P4: L3 + E ----
#pragma unroll
  for (int s = 0; s < 2; ++s) {
    if (s) __syncthreads();
    low_body<2>(tid, b, (idx << 1) | s, tf[3], 0.f, cp12[3], swapb, ptab, smask,
                sfull, sdeg, wsum, hp8, state, out);
  }
}

extern "C" void kernel_launch(void* const* d_in, const int* in_sizes, int n_in,
                              void* d_out, int out_size, void* d_ws, size_t ws_size,
                              hipStream_t stream) {
  const float* betas = (const float*)d_in[0];  // [8][4]
  const float* adj   = (const float*)d_in[1];  // [8][18][18]
  float* out = (float*)d_out;                  // [8] float32
  char* ws = (char*)d_ws;
  u32* state = (u32*)ws;                                              // 8 MB (half2)
  unsigned char* hp8 = (unsigned char*)(ws + (size_t)NB * QDIM * 4);  // 2 MB
  u32* bar = (u32*)(ws + (size_t)NB * QDIM * 5);                      // 512 B

  k_init<<<1, 192, 0, stream>>>(bar, out);
  k_fused<<<256, 512, 0, stream>>>(betas, adj, hp8, state, out, bar);
}

// Round 12
// 41.513 us; speedup vs baseline: 1.0876x; 1.0876x over previous
//
#include <hip/hip_runtime.h>
#include <hip/hip_fp16.h>

#define NQ 18
#define QDIM (1 << NQ)      // 262144
#define NB 8
#define NL 4

typedef unsigned u32;
typedef unsigned long long u64;
typedef float f32x2 __attribute__((ext_vector_type(2)));

#define DPP_XOR1 0xB1   // quad_perm [1,0,3,2]  (lane bit 0)
#define DPP_XOR2 0x4E   // quad_perm [2,3,0,1]  (lane bit 1)

// d = s0 * swap(s1) + s2 where swap((x,y)) = (y,x), via VOP3P op_sel on src1.
// lo: s0.lo*s1.hi + s2.lo ; hi: s0.hi*s1.lo + s2.hi
__device__ __forceinline__ f32x2 pkfma_swap1(f32x2 s0, f32x2 s1, f32x2 s2) {
  f32x2 d;
  asm("v_pk_fma_f32 %0, %1, %2, %3 op_sel:[0,1,0] op_sel_hi:[1,0,1]"
      : "=v"(d) : "v"(s0), "v"(s1), "v"(s2));
  return d;
}

// tan-form butterfly with tt = (t,-t): a' = a + t*(b.y,-b.x); b' = b + t*(a.y,-a.x)
// = ONE v_pk_fma_f32 per output (vs 4 scalar FMA per pair before).
__device__ __forceinline__ void tbfly(f32x2& a, f32x2& b, f32x2 tt) {
  f32x2 na = pkfma_swap1(tt, b, a);
  f32x2 nb = pkfma_swap1(tt, a, b);
  a = na; b = nb;
}
__device__ __forceinline__ void tstage(f32x2* v, int m, f32x2 tt) {
#pragma unroll
  for (int i = 0; i < 16; ++i)
    if (!(i & m)) tbfly(v[i], v[i | m], tt);
}
// cross-lane butterfly via DPP + one pk_fma (swap folded into op_sel)
template <int CTRL>
__device__ __forceinline__ void dppstage(f32x2* v, f32x2 tt) {
#pragma unroll
  for (int k = 0; k < 16; ++k) {
    f32x2 o;
    o[0] = __int_as_float(
        __builtin_amdgcn_mov_dpp(__float_as_int(v[k][0]), CTRL, 0xF, 0xF, true));
    o[1] = __int_as_float(
        __builtin_amdgcn_mov_dpp(__float_as_int(v[k][1]), CTRL, 0xF, 0xF, true));
    v[k] = pkfma_swap1(tt, o, v[k]);
  }
}
// 6-bit mix: 4 reg bits + lane bits 0,1 (dpp). Stages commute.
__device__ __forceinline__ void mix6(f32x2* v, f32x2 tt) {
  tstage(v, 1, tt); tstage(v, 2, tt); tstage(v, 4, tt); tstage(v, 8, tt);
  dppstage<DPP_XOR1>(v, tt); dppstage<DPP_XOR2>(v, tt);
}
__device__ __forceinline__ void pmul(f32x2& a, f32x2 p) {
  a = f32x2{a[0] * p[0] - a[1] * p[1], a[0] * p[1] + a[1] * p[0]};
}
// LDS swizzle: XOR byte bits 4-6 with bits 7-9. Involution, both sides.
__device__ __forceinline__ int swz(int byte) { return byte ^ (((byte >> 7) & 7) << 4); }

__device__ __forceinline__ f32x2 h2f(u32 u) {
  __half2 h; *(u32*)&h = u;
  float2 f = __half22float2(h);
  return f32x2{f.x, f.y};
}
__device__ __forceinline__ u32 f2h(f32x2 f) {
  __half2 h = __float22half2_rn(make_float2(f[0], f[1]));
  return *(u32*)&h;
}

// ---------------- low pass: element bits 0..11 ----------------
// 256 thr, 16 elems/thread, tile 4096; b = blockIdx&7 (XCD pin), blk6 = blockIdx>>3.
//  A: le = tid<<4 | j          (reg j = bits 0-3; lane0,1 = bits 4,5) <- global I/O
//  B: le = j<<8 | (l&3)<<6 | w<<4 | (l>>2)   (reg j = bits 8-11; lane0,1 = bits 6,7)
// MODE 0: gray-code hp @A, init, mixA(t0), swap, mixB(t0), swap, store @A
// MODE 1: load @A, mixA(t0), swap, mixB(t0), D @B, mixB(t1), swap, mixA(t1), store
// MODE 2: load @A, mixA(t0), swap, mixB(t0), energy @B -> atomicAdd
template <int MODE>
__global__ __launch_bounds__(256)
void k_low(const float* __restrict__ betas, const float* __restrict__ adj,
           unsigned char* __restrict__ hp8, u32* __restrict__ state,
           float* __restrict__ out, int t0) {
  __shared__ f32x2 swapb[4096];   // 32 KB
  __shared__ f32x2 ptab[160];
  __shared__ unsigned smask[NQ];
  __shared__ unsigned sfull[4];
  __shared__ int sdeg[4];
  __shared__ float wsum[4];

  const int tid = threadIdx.x;
  const int l = tid & 63, w = tid >> 6;
  const int b = blockIdx.x & 7;        // XCD-aligned batch
  const int blk6 = blockIdx.x >> 3;    // element bits 12-17
  const size_t bb = (size_t)b << NQ;
  const int lbase = blk6 << 12;
  char* L = (char*)swapb;
  const int leB = ((l & 3) << 6) | (w << 4) | ((l >> 2) & 15);
  const int bB  = leB << 3;

  const float beta0 = betas[b * NL + t0];
  float s0, c0; sincosf(beta0, &s0, &c0);
  const float tf0 = s0 / c0;
  const f32x2 tt0 = f32x2{tf0, -tf0};
  const float c0p2 = c0 * c0, c0p4 = c0p2 * c0p2;
  const float c0p12 = c0p4 * c0p4 * c0p4;

  f32x2 tt1 = f32x2{0.f, 0.f};
  float scale = 1.f;
  if (MODE == 0) scale = 0.001953125f * c0p12;   // 1/sqrt(2^18) * cos^12
  if (MODE == 1) {
    const float beta1 = betas[b * NL + t0 + 1];
    float s1, c1; sincosf(beta1, &s1, &c1);
    const float tf1 = s1 / c1;
    tt1 = f32x2{tf1, -tf1};
    const float c1p2 = c1 * c1, c1p4 = c1p2 * c1p2;
    scale = c0p12 * (c1p4 * c1p4 * c1p4);
  }

  if (MODE == 0) {
    if (tid < NQ) {
      unsigned m = 0;
      const float* row = adj + ((size_t)b * NQ + tid) * NQ;
      for (int vq = tid + 1; vq < NQ; ++vq)
        if (row[vq] > 0.5f) m |= 1u << (NQ - 1 - vq);
      smask[tid] = m;
    }
    if (blk6 == 0 && tid == 0) out[b] = 0.f;  // P1 completes before P5 launches
    __syncthreads();
    if (tid < 4) {  // full neighbor masks for element bits 0-3 (qubit 17-p)
      unsigned fm = smask[17 - tid];
      for (int uq = 0; uq < NQ; ++uq)
        if ((smask[uq] >> tid) & 1u) fm |= 1u << (17 - uq);
      sfull[tid] = fm; sdeg[tid] = __popc(fm);
    }
  }
  if (MODE != 2 && tid < 160) {
    float ss, cc; sincosf((float)tid, &ss, &cc);
    ptab[tid] = f32x2{cc * scale, -ss * scale};  // e^{-i h} * scale
  }

  f32x2 v[16];

  if (MODE == 0) {
    __syncthreads();
    // hp via gray code over element bits 0-3 (A regs)
    unsigned d = (unsigned)(lbase | (tid << 4));
    int hp = 0;
#pragma unroll
    for (int uq = 0; uq < NQ; ++uq) {
      const unsigned f = (d >> (17 - uq)) & 1u;
      hp += __popc(smask[uq] & (d ^ (0u - f)));
    }
    u64 plo = (u64)hp, phi = 0;
    int j = 0;
#pragma unroll
    for (int i = 1; i < 16; ++i) {
      const int p = __ffs(i) - 1;
      const int old = (int)((d >> p) & 1u);
      const int nb1 = __popc(sfull[p] & d);
      hp += old ? (2 * nb1 - sdeg[p]) : (sdeg[p] - 2 * nb1);
      d ^= 1u << p; j ^= 1 << p;
      if (j < 8) plo |= (u64)hp << (8 * j);
      else       phi |= (u64)hp << (8 * (j - 8));
    }
    uint4 hq;
    hq.x = (unsigned)plo; hq.y = (unsigned)(plo >> 32);
    hq.z = (unsigned)phi; hq.w = (unsigned)(phi >> 32);
    *(uint4*)(hp8 + bb + (size_t)(lbase + (tid << 4))) = hq;
#pragma unroll
    for (int jj = 0; jj < 16; ++jj) {
      const int h = (jj < 8) ? (int)((plo >> (8 * jj)) & 255)
                             : (int)((phi >> (8 * (jj - 8))) & 255);
      v[jj] = ptab[h];
    }
    mix6(v, tt0);                                 // bits 0-5
#pragma unroll
    for (int q = 0; q < 8; ++q)                   // swap A -> B
      *(float4*)(L + swz((tid << 7) + (q << 4))) =
          make_float4(v[2*q][0], v[2*q][1], v[2*q+1][0], v[2*q+1][1]);
    __syncthreads();
#pragma unroll
    for (int jj = 0; jj < 16; ++jj)
      v[jj] = *(const f32x2*)(L + swz((jj << 11) + bB));
    mix6(v, tt0);                                 // bits 6-11
#pragma unroll
    for (int jj = 0; jj < 16; ++jj)               // swap B -> A
      *(f32x2*)(L + swz((jj << 11) + bB)) = v[jj];
    __syncthreads();
#pragma unroll
    for (int q = 0; q < 8; ++q) {
      const float4 f = *(const float4*)(L + swz((tid << 7) + (q << 4)));
      v[2*q]   = f32x2{f.x, f.y};
      v[2*q+1] = f32x2{f.z, f.w};
    }
    uint4* gdst = (uint4*)(state + bb + lbase + (tid << 4));
#pragma unroll
    for (int q = 0; q < 4; ++q) {
      uint4 t4;
      t4.x = f2h(v[4*q]);   t4.y = f2h(v[4*q+1]);
      t4.z = f2h(v[4*q+2]); t4.w = f2h(v[4*q+3]);
      gdst[q] = t4;
    }
    return;
  }

  // MODE 1 / 2: load @A (vectorized), mixA(t0), swap -> B, mixB(t0)
  const uint4* gsrc = (const uint4*)(state + bb + lbase + (tid << 4));
#pragma unroll
  for (int q = 0; q < 4; ++q) {
    const uint4 t4 = gsrc[q];
    v[4*q]   = h2f(t4.x); v[4*q+1] = h2f(t4.y);
    v[4*q+2] = h2f(t4.z); v[4*q+3] = h2f(t4.w);
  }
  mix6(v, tt0);                                   // bits 0-5
#pragma unroll
  for (int q = 0; q < 8; ++q)
    *(float4*)(L + swz((tid << 7) + (q << 4))) =
        make_float4(v[2*q][0], v[2*q][1], v[2*q+1][0], v[2*q+1][1]);
  __syncthreads();
#pragma unroll
  for (int jj = 0; jj < 16; ++jj)
    v[jj] = *(const f32x2*)(L + swz((jj << 11) + bB));
  mix6(v, tt0);                                   // bits 6-11

  if (MODE == 1) {
    const unsigned char* hq = hp8 + bb + (size_t)(lbase + leB);
#pragma unroll
    for (int jj = 0; jj < 16; ++jj)
      pmul(v[jj], ptab[hq[jj << 8]]);             // diagonal @B
    mix6(v, tt1);                                 // bits 6-11
#pragma unroll
    for (int jj = 0; jj < 16; ++jj)               // swap B -> A
      *(f32x2*)(L + swz((jj << 11) + bB)) = v[jj];
    __syncthreads();
#pragma unroll
    for (int q = 0; q < 8; ++q) {
      const float4 f = *(const float4*)(L + swz((tid << 7) + (q << 4)));
      v[2*q]   = f32x2{f.x, f.y};
      v[2*q+1] = f32x2{f.z, f.w};
    }
    mix6(v, tt1);                                 // bits 0-5
    uint4* gdst = (uint4*)(state + bb + lbase + (tid << 4));
#pragma unroll
    for (int q = 0; q < 4; ++q) {
      uint4 t4;
      t4.x = f2h(v[4*q]);   t4.y = f2h(v[4*q+1]);
      t4.z = f2h(v[4*q+2]); t4.w = f2h(v[4*q+3]);
      gdst[q] = t4;
    }
  } else {  // MODE 2: energy @B; scale before squaring
    const unsigned char* hq = hp8 + bb + (size_t)(lbase + leB);
    float acc = 0.f;
#pragma unroll
    for (int jj = 0; jj < 16; ++jj) {
      const float h = (float)hq[jj << 8];
      const float wx = v[jj][0] * c0p12, wy = v[jj][1] * c0p12;
      acc = fmaf(wx * wx + wy * wy, h, acc);
    }
#pragma unroll
    for (int m = 1; m <= 32; m <<= 1) acc += __shfl_xor(acc, m, 64);
    if (l == 0) wsum[w] = acc;
    __syncthreads();
    if (tid == 0) atomicAdd(out + b, wsum[0] + wsum[1] + wsum[2] + wsum[3]);
  }
}

// ---------------- high pass: element bits 12..17 ----------------
// 256 thr: w2 = tid>>6, lane = cols (bits 0-5), mid = blockIdx>>3 (bits 6-11).
// p0 rows = w2<<4|j (j = bits 12-15); p1 rows = j<<2|w2 (stages 16-17 = masks 4,8).
// [H_t0, D, H_t1]
__global__ __launch_bounds__(256)
void k_high(const float* __restrict__ betas, const unsigned char* __restrict__ hp8,
            u32* __restrict__ state, int t0) {
  __shared__ f32x2 swapb[4096];
  __shared__ f32x2 ptab[160];
  const int tid = threadIdx.x;
  const int w2 = tid >> 6, lane = tid & 63;
  const int b = blockIdx.x & 7;        // XCD-aligned batch
  const int mid = blockIdx.x >> 3;     // element bits 6-11
  const size_t bb = (size_t)b << NQ;
  const int base = (mid << 6) | lane;

  const float beta0 = betas[b * NL + t0], beta1 = betas[b * NL + t0 + 1];
  float s0, c0, s1, c1;
  sincosf(beta0, &s0, &c0); sincosf(beta1, &s1, &c1);
  const float tf0 = s0 / c0, tf1 = s1 / c1;
  const f32x2 tt0 = f32x2{tf0, -tf0}, tt1 = f32x2{tf1, -tf1};
  const float c0p2 = c0 * c0, c1p2 = c1 * c1;
  const float scale = (c0p2 * c0p2 * c0p2) * (c1p2 * c1p2 * c1p2);  // cos^6 each
  if (tid < 160) {
    float ss, cc; sincosf((float)tid, &ss, &cc);
    ptab[tid] = f32x2{cc * scale, -ss * scale};
  }

  f32x2 v[16];
#pragma unroll
  for (int j = 0; j < 16; ++j)
    v[j] = h2f(state[bb + ((size_t)((w2 << 4) | j) << 12) + base]);
  tstage(v, 1, tt0); tstage(v, 2, tt0); tstage(v, 4, tt0); tstage(v, 8, tt0);
#pragma unroll
  for (int j = 0; j < 16; ++j)
    swapb[(((w2 << 4) | j) << 6) | lane] = v[j];
  __syncthreads();
#pragma unroll
  for (int j = 0; j < 16; ++j)
    v[j] = swapb[(((j << 2) | w2) << 6) | lane];
  tstage(v, 4, tt0); tstage(v, 8, tt0);           // bits 16-17
#pragma unroll
  for (int j = 0; j < 16; ++j) {
    const int h = hp8[bb + ((size_t)((j << 2) | w2) << 12) + base];
    pmul(v[j], ptab[h]);
  }
  tstage(v, 4, tt1); tstage(v, 8, tt1);           // bits 16-17
#pragma unroll
  for (int j = 0; j < 16; ++j)
    swapb[(((j << 2) | w2) << 6) | lane] = v[j];
  __syncthreads();
#pragma unroll
  for (int j = 0; j < 16; ++j)
    v[j] = swapb[(((w2 << 4) | j) << 6) | lane];
  tstage(v, 1, tt1); tstage(v, 2, tt1); tstage(v, 4, tt1); tstage(v, 8, tt1);
#pragma unroll
  for (int j = 0; j < 16; ++j)
    state[bb + ((size_t)((w2 << 4) | j) << 12) + base] = f2h(v[j]);
}

extern "C" void kernel_launch(void* const* d_in, const int* in_sizes, int n_in,
                              void* d_out, int out_size, void* d_ws, size_t ws_size,
                              hipStream_t stream) {
  const float* betas = (const float*)d_in[0];  // [8][4]
  const float* adj   = (const float*)d_in[1];  // [8][18][18]
  float* out = (float*)d_out;                  // [8] float32
  char* ws = (char*)d_ws;
  u32* state = (u32*)ws;                                              // 8 MB (half2)
  unsigned char* hp8 = (unsigned char*)(ws + (size_t)NB * QDIM * 4);  // 2 MB

  dim3 grid(NB * 64), blk(256);
  // P1: D + L0      P2: H0 D H1      P3: L1 D L2      P4: H2 D H3      P5: L3 + E
  k_low<0><<<grid, blk, 0, stream>>>(betas, adj, hp8, state, out, 0);
  k_high  <<<grid, blk, 0, stream>>>(betas, hp8, state, 0);
  k_low<1><<<grid, blk, 0, stream>>>(betas, adj, hp8, state, out, 1);
  k_high  <<<grid, blk, 0, stream>>>(betas, hp8, state, 2);
  k_low<2><<<grid, blk, 0, stream>>>(betas, adj, hp8, state, out, 3);
}